// Round 1
// baseline (536.098 us; speedup 1.0000x reference)
//
#include <hip/hip_runtime.h>
#include <hip/hip_bf16.h>
#include <stdint.h>

typedef unsigned int u32;
typedef unsigned short u16;

#define F 128

typedef __attribute__((ext_vector_type(8))) short bf16x8;
typedef __attribute__((ext_vector_type(4))) float f32x4;

__device__ __forceinline__ float bf2f(u16 v){
  union { u32 u; float f; } x; x.u = ((u32)v) << 16; return x.f;
}
__device__ __forceinline__ u16 f2bf(float f){
  union { float f; u32 u; } x; x.f = f;
  u32 u = x.u;
  return (u16)((u + 0x7fffu + ((u >> 16) & 1u)) >> 16);   // RNE
}

// ---- merged dtype / edge-layout detection -----------------------------------
// block 0: f32 words have uniform-random bits[14:7]; bf16 pair data of
// ~N(0,1)/glorot never has low-half "exponent" > 160  -> flags[1]
// block 1: int64 edge values < 50000 -> all odd 32b words are 0 -> flags[0]
__global__ void k_flags(const u32* __restrict__ xw, const u32* __restrict__ ei,
                        int* __restrict__ flags){
  if (blockIdx.x == 0){
    u32 hit = 0;
    for (int i = threadIdx.x; i < 2048; i += 256){
      u32 e = (xw[i] >> 7) & 0xFFu;
      if (e > 160u) hit = 1;
    }
    if (hit) atomicOr(&flags[1], 1);
  } else {
    u32 v = 0;
    for (int i = threadIdx.x; i < 4096; i += 256) v |= ei[2*i + 1];
    if (v) atomicOr(&flags[0], 1);
  }
}

// ---- bucketed CSR build (256-node buckets) ----------------------------------
__launch_bounds__(256)
__global__ void k_bhist(const u32* __restrict__ w, int E, const int* __restrict__ flagp,
                        int NB, int* __restrict__ bcnt){
  __shared__ int h[256];
  int st = (*flagp) ? 1 : 2;
  int t = threadIdx.x;
  h[t] = 0;
  __syncthreads();
  int base = blockIdx.x*4096;
  #pragma unroll 4
  for (int k = 0; k < 16; k++){
    int i = base + k*256 + t;
    if (i < E){
      int d = (int)w[(size_t)(E + i)*st];
      atomicAdd(&h[d >> 8], 1);
    }
  }
  __syncthreads();
  if (t < NB && h[t]) atomicAdd(&bcnt[t], h[t]);
}

__global__ void k_bscan(const int* __restrict__ bcnt, int NB, int E,
                        int* __restrict__ bbase, int* __restrict__ bump){
  __shared__ int s[256];
  int t = threadIdx.x;
  int v = (t < NB) ? bcnt[t] : 0;
  s[t] = v;
  __syncthreads();
  for (int off = 1; off < 256; off <<= 1){
    int x = (t >= off) ? s[t - off] : 0;
    __syncthreads();
    s[t] += x;
    __syncthreads();
  }
  bbase[t] = s[t] - v;            // exclusive; == E for t >= NB
  if (t == 255) bbase[256] = E;
  bump[t] = 0;
}

__launch_bounds__(256)
__global__ void k_msplit(const u32* __restrict__ w, int E, const int* __restrict__ flagp,
                         const int* __restrict__ bbase, int* __restrict__ bump,
                         u32* __restrict__ ebuf){
  __shared__ int h[256];
  __shared__ int cb[256];
  int st = (*flagp) ? 1 : 2;
  int t = threadIdx.x;
  h[t] = 0;
  __syncthreads();
  int base = blockIdx.x*4096;
  u32 ps[16]; int bk[16]; int rk[16];
  #pragma unroll 4
  for (int k = 0; k < 16; k++){
    int i = base + k*256 + t;
    if (i < E){
      u32 s = w[(size_t)i*st];
      u32 d = w[(size_t)(E + i)*st];
      bk[k] = (int)(d >> 8);
      ps[k] = (s & 0xFFFFu) | ((d & 0xFFu) << 16);
      rk[k] = atomicAdd(&h[bk[k]], 1);
    } else bk[k] = -1;
  }
  __syncthreads();
  cb[t] = h[t] ? (bbase[t] + atomicAdd(&bump[t], h[t])) : 0;
  __syncthreads();
  #pragma unroll 4
  for (int k = 0; k < 16; k++){
    if (bk[k] >= 0) ebuf[cb[bk[k]] + rk[k]] = ps[k];
  }
}

// per-bucket deg/rs/csr emit + dis = rsqrt(1+deg) folded in
__launch_bounds__(256)
__global__ void k_bemit(const u32* __restrict__ ebuf, const int* __restrict__ bbase,
                        int N, int* __restrict__ deg, int* __restrict__ rs,
                        u16* __restrict__ csr, float* __restrict__ dis){
  __shared__ int nd[256];
  __shared__ int nofs[256];
  __shared__ int s[256];
  int b = blockIdx.x;
  int t = threadIdx.x;
  int e0 = bbase[b], e1 = bbase[b + 1];
  nd[t] = 0;
  __syncthreads();
  for (int i = e0 + t; i < e1; i += 256) atomicAdd(&nd[ebuf[i] >> 16], 1);
  __syncthreads();
  int v = nd[t];
  s[t] = v;
  __syncthreads();
  for (int off = 1; off < 256; off <<= 1){
    int x = (t >= off) ? s[t - off] : 0;
    __syncthreads();
    s[t] += x;
    __syncthreads();
  }
  nofs[t] = s[t] - v;
  int node = b*256 + t;
  if (node < N){
    deg[node] = v;
    rs[node]  = e0 + nofs[t];
    dis[node] = rsqrtf(1.0f + (float)v);
  }
  nd[t] = 0;               // reuse as fill
  __syncthreads();
  for (int i = e0 + t; i < e1; i += 256){
    u32 p = ebuf[i];
    int d = (int)(p >> 16);
    int pos = e0 + nofs[d] + atomicAdd(&nd[d], 1);
    csr[pos] = (u16)(p & 0xFFFFu);
  }
}

// ---- merged small-tensor prep: bb[3][128], wf4[128], bb4[1] -----------------
__global__ void k_prep(const void* b1, const void* b2, const void* b3,
                       const void* W4, const void* b4, const int* __restrict__ isf32,
                       float* __restrict__ bb, float* __restrict__ wf4,
                       float* __restrict__ bb4){
  int t = threadIdx.x;
  int f32 = *isf32;
  if (t < 384){
    const void* s = (t < 128) ? b1 : ((t < 256) ? b2 : b3);
    int i = t & 127;
    bb[t] = f32 ? ((const float*)s)[i] : bf2f(((const u16*)s)[i]);
  } else if (t < 512){
    int i = t - 384;
    wf4[i] = f32 ? ((const float*)W4)[i] : bf2f(((const u16*)W4)[i]);
  } else if (t == 512){
    bb4[0] = f32 ? ((const float*)b4)[0] : bf2f(((const u16*)b4)[0]);
  }
}

// dual-dtype input -> bf16 in SLICED layout X_t[c][r][32], c = f>>5
__global__ void k_cvt_b(const void* __restrict__ in, const int* __restrict__ isf32,
                        u16* __restrict__ out, int N){
  int i = blockIdx.x*blockDim.x + threadIdx.x;
  int n = N*F;
  if (i < n){
    int r = i >> 7, f = i & 127;
    float v = (*isf32) ? ((const float*)in)[i] : bf2f(((const u16*)in)[i]);
    __builtin_nontemporal_store(f2bf(v), &out[((size_t)(f >> 5)*N + r)*32 + (f & 31)]);
  }
}

// Swizzle W[128][128] x3 (dual dtype) into MFMA B-fragment order:
// WL[l][ct][kb][lane][j] = bf16(W[kb*32 + (lane>>4)*8 + j][ct*16 + (lane&15)])
__global__ void k_swz3(const void* W1, const void* W2, const void* W3,
                       const int* __restrict__ isf32, u16* __restrict__ WL){
  int l = blockIdx.x >> 6;
  const void* W = (l == 0) ? W1 : ((l == 1) ? W2 : W3);
  int idx = (blockIdx.x & 63)*256 + threadIdx.x;   // 0..16383
  int j    = idx & 7;
  int lane = (idx >> 3) & 63;
  int kb   = (idx >> 9) & 3;
  int ct   = idx >> 11;
  int m = lane & 15, q = lane >> 4;
  int k = kb*32 + q*8 + j;
  int c = ct*16 + m;
  float v = (*isf32) ? ((const float*)W)[k*F + c] : bf2f(((const u16*)W)[k*F + c]);
  WL[l*16384 + idx] = f2bf(v);
}

// G_t[c][r][32] = dis[r] * (X @ W)[r][c*32..], MFMA 16x16x32 bf16.
// A-loads: elems kb*32+q*8+j all lie in chunk kb -> contiguous 1KB per wave per kb.
__launch_bounds__(256)
__global__ void k_mm(const u16* __restrict__ X, const u16* __restrict__ WL,
                     const float* __restrict__ dis, u16* __restrict__ G, int N){
  int w = threadIdx.x >> 6, lane = threadIdx.x & 63;
  int m = lane & 15, q = lane >> 4;
  int row0 = blockIdx.x*64 + w*16;
  int arow = row0 + m;
  bf16x8 a[4];
  if (arow < N){
    #pragma unroll
    for (int kb = 0; kb < 4; kb++)
      a[kb] = *(const bf16x8*)(X + ((size_t)kb*N + arow)*32 + q*8);
  } else {
    #pragma unroll
    for (int kb = 0; kb < 4; kb++) a[kb] = (bf16x8){0,0,0,0,0,0,0,0};
  }
  f32x4 acc[8];
  #pragma unroll
  for (int ct = 0; ct < 8; ct++) acc[ct] = (f32x4){0.f,0.f,0.f,0.f};
  #pragma unroll
  for (int ct = 0; ct < 8; ct++){
    #pragma unroll
    for (int kb = 0; kb < 4; kb++){
      bf16x8 b = *(const bf16x8*)(WL + ((size_t)((ct*4 + kb)*64 + lane))*8);
      acc[ct] = __builtin_amdgcn_mfma_f32_16x16x32_bf16(a[kb], b, acc[ct], 0, 0, 0);
    }
  }
  int rbase = row0 + q*4;
  #pragma unroll
  for (int r = 0; r < 4; r++){
    int row = rbase + r;
    if (row < N){
      float dv = dis[row];
      #pragma unroll
      for (int ct = 0; ct < 8; ct++){
        // feat = ct*16+m -> chunk ct>>1, elem (ct&1)*16+m
        __builtin_nontemporal_store(f2bf(dv*acc[ct][r]),
            &G[((size_t)(ct >> 1)*N + row)*32 + (ct & 1)*16 + m]);
      }
    }
  }
}

// XCD-pinned sliced aggregation. Block handles 4 consecutive nodes for ONE
// 32-feature slice c=(blockIdx%8)>>1; blocks round-robin across XCDs, so each
// XCD-pair gathers only its own 3.2 MB slice of G -> L2-resident gathers.
// Wave: lane = slot(4)*16 + fp(16); 4 neighbors in flight per u32-load instr,
// 16-deep unrolled; slot-reduce with shfl_xor(16/32) at the end.
__launch_bounds__(256)
__global__ void k_agg(const u16* __restrict__ G, const float* __restrict__ dis,
                      const int* __restrict__ rs, const int* __restrict__ deg,
                      const u16* __restrict__ csr, const float* __restrict__ bias,
                      u16* __restrict__ Xout, int N, int relu){
  int c    = (blockIdx.x & 7) >> 1;                              // slice 0..3
  int wid  = (blockIdx.x >> 3)*8 + (blockIdx.x & 1)*4 + (threadIdx.x >> 6);
  int lane = threadIdx.x & 63;
  int slot = lane >> 4;        // 0..3
  int fp   = lane & 15;        // feature pair within slice
  if (wid >= N) return;
  const u16* Gs = G + (size_t)c*N*32;
  int base = rs[wid], len = deg[wid];
  float p0=0.f,p1=0.f,p2=0.f,p3=0.f,q0=0.f,q1=0.f,q2=0.f,q3=0.f;
  for (int j = 0; j < len; j += 16){
    int n0 = j + slot, n1 = j + 4 + slot, n2 = j + 8 + slot, n3 = j + 12 + slot;
    u32 w0 = 0, w1 = 0, w2 = 0, w3 = 0;
    if (n0 < len){ int s = csr[base + n0]; w0 = *(const u32*)(Gs + (size_t)s*32 + 2*fp); }
    if (n1 < len){ int s = csr[base + n1]; w1 = *(const u32*)(Gs + (size_t)s*32 + 2*fp); }
    if (n2 < len){ int s = csr[base + n2]; w2 = *(const u32*)(Gs + (size_t)s*32 + 2*fp); }
    if (n3 < len){ int s = csr[base + n3]; w3 = *(const u32*)(Gs + (size_t)s*32 + 2*fp); }
    p0 += bf2f((u16)w0); q0 += bf2f((u16)(w0 >> 16));
    p1 += bf2f((u16)w1); q1 += bf2f((u16)(w1 >> 16));
    p2 += bf2f((u16)w2); q2 += bf2f((u16)(w2 >> 16));
    p3 += bf2f((u16)w3); q3 += bf2f((u16)(w3 >> 16));
  }
  float a0 = (p0 + p1) + (p2 + p3);
  float a1 = (q0 + q1) + (q2 + q3);
  a0 += __shfl_xor(a0, 16, 64); a0 += __shfl_xor(a0, 32, 64);
  a1 += __shfl_xor(a1, 16, 64); a1 += __shfl_xor(a1, 32, 64);
  if (slot == 0){
    u32 sw = *(const u32*)(Gs + (size_t)wid*32 + 2*fp);   // self term
    a0 += bf2f((u16)sw); a1 += bf2f((u16)(sw >> 16));
    float dv = dis[wid];
    float o0 = fmaf(dv, a0, bias[c*32 + 2*fp]);
    float o1 = fmaf(dv, a1, bias[c*32 + 2*fp + 1]);
    if (relu){ o0 = fmaxf(o0, 0.f); o1 = fmaxf(o1, 0.f); }
    u32 pk = (u32)f2bf(o0) | ((u32)f2bf(o1) << 16);
    __builtin_nontemporal_store(pk, (u32*)(Xout + ((size_t)c*N + wid)*32 + 2*fp));
  }
}

// layer 4 matmul: G4[n] = dis[n] * dot(X_t[:,n,:], W4f); one wave per node
__global__ void k_mm4(const u16* __restrict__ X, const float* __restrict__ W4f,
                      const float* __restrict__ dis, float* __restrict__ G4, int N){
  int gt   = blockIdx.x*blockDim.x + threadIdx.x;
  int wid  = gt >> 6;
  int lane = threadIdx.x & 63;
  if (wid >= N) return;
  // feats 2*lane,2*lane+1 -> chunk lane>>4, elem 2*(lane&15)
  u32 xw = *(const u32*)(X + ((size_t)(lane >> 4)*N + wid)*32 + 2*(lane & 15));
  float acc = bf2f((u16)xw)*W4f[2*lane] + bf2f((u16)(xw >> 16))*W4f[2*lane + 1];
  #pragma unroll
  for (int off = 32; off > 0; off >>= 1) acc += __shfl_down(acc, off, 64);
  if (lane == 0) G4[wid] = dis[wid]*acc;
}

__global__ void k_agg4(const float* __restrict__ G4, const float* __restrict__ dis,
                       const int* __restrict__ rs, const int* __restrict__ deg,
                       const u16* __restrict__ csr, const float* __restrict__ b4f,
                       const int* __restrict__ isf32, void* __restrict__ out, int N){
  int i = blockIdx.x*blockDim.x + threadIdx.x;
  if (i >= N) return;
  int base = rs[i], len = deg[i];
  float a0 = 0.f, a1 = 0.f, a2 = 0.f, a3 = 0.f;
  int j = 0;
  for (; j + 4 <= len; j += 4){
    int s0 = csr[base + j],     s1 = csr[base + j + 1];
    int s2 = csr[base + j + 2], s3 = csr[base + j + 3];
    a0 += G4[s0]; a1 += G4[s1]; a2 += G4[s2]; a3 += G4[s3];
  }
  for (; j < len; j++) a0 += G4[csr[base + j]];
  float r = dis[i]*(G4[i] + ((a0 + a1) + (a2 + a3))) + b4f[0];
  if (*isf32) ((float*)out)[i] = r;
  else        ((u16*)out)[i]   = f2bf(r);
}

extern "C" void kernel_launch(void* const* d_in, const int* in_sizes, int n_in,
                              void* d_out, int out_size, void* d_ws, size_t ws_size,
                              hipStream_t stream){
  const void* x0 = d_in[0];
  const u32*  ei = (const u32*)d_in[1];
  const void* Wp[4] = {d_in[2], d_in[4], d_in[6], d_in[8]};
  const void* bp[4] = {d_in[3], d_in[5], d_in[7], d_in[9]};
  int N = in_sizes[0] / F;       // 50000
  int E = in_sizes[1] / 2;       // 1,600,000
  int NB = (N + 255) >> 8;       // 196 buckets

  char* base = (char*)d_ws;
  size_t off = 0;
  auto alloc = [&](size_t bytes)->char*{
    char* p = base + off;
    off = (off + bytes + 255) & ~(size_t)255;
    return p;
  };
  int*   deg  = (int*)  alloc((size_t)N*4);
  float* dis  = (float*)alloc((size_t)N*4);
  int*   rs   = (int*)  alloc((size_t)N*4);
  float* g4   = (float*)alloc((size_t)N*4);
  int*   bcnt = (int*)  alloc(1024);
  int*   bbase= (int*)  alloc(1056);           // 257 ints
  int*   bump = (int*)  alloc(1024);
  int*   flags= (int*)  alloc(256);            // [0]=int32-edge flag, [1]=isf32
  u32*   ebuf = (u32*)  alloc((size_t)E*4);    // bucketed packed edges, 6.4 MB
  u16*   csr  = (u16*)  alloc((size_t)E*2);    // 3.2 MB
  u16*   WL   = (u16*)  alloc(3*16384*2);      // swizzled W1..W3, 96 KB
  float* wf4  = (float*)alloc(F*4);
  float* bb   = (float*)alloc(3*F*4);          // biases b1..b3
  float* bb4  = (float*)alloc(256);
  u16*   gbuf = (u16*)  alloc((size_t)N*F*2);  // 12.8 MB, sliced [4][N][32]
  u16*   xbuf = (u16*)  alloc((size_t)N*F*2);  // 12.8 MB, sliced [4][N][32]

  hipMemsetAsync(bcnt, 0, 1024, stream);
  hipMemsetAsync(flags, 0, 256, stream);

  int* eflag = flags + 0;
  int* isf32 = flags + 1;

  int nbt = (N + 255)/256;
  int etb = (E + 4095)/4096;

  k_flags <<<2, 256, 0, stream>>>((const u32*)x0, ei, flags);
  k_bhist <<<etb, 256, 0, stream>>>(ei, E, eflag, NB, bcnt);
  k_bscan <<<1, 256, 0, stream>>>(bcnt, NB, E, bbase, bump);
  k_msplit<<<etb, 256, 0, stream>>>(ei, E, eflag, bbase, bump, ebuf);
  k_bemit <<<NB, 256, 0, stream>>>(ebuf, bbase, N, deg, rs, csr, dis);
  k_prep  <<<1, 640, 0, stream>>>(bp[0], bp[1], bp[2], Wp[3], bp[3], isf32, bb, wf4, bb4);
  k_swz3  <<<192, 256, 0, stream>>>(Wp[0], Wp[1], Wp[2], isf32, WL);
  k_cvt_b <<<((size_t)N*F + 255)/256, 256, 0, stream>>>(x0, isf32, xbuf, N);

  int mmb  = (N + 63)/64;
  int aggB = ((N + 7)/8)*8;      // 4 nodes/block x 8 (slice,parity) variants

  for (int l = 0; l < 3; l++){
    k_mm <<<mmb, 256, 0, stream>>>(xbuf, WL + l*16384, dis, gbuf, N);
    k_agg<<<aggB, 256, 0, stream>>>(gbuf, dis, rs, deg, csr, bb + l*F, xbuf, N, 1);
  }
  k_mm4 <<<((size_t)N*64 + 255)/256, 256, 0, stream>>>(xbuf, wf4, dis, g4, N);
  k_agg4<<<nbt, 256, 0, stream>>>(g4, dis, rs, deg, csr, bb4, isf32, (void*)d_out, N);
}

// Round 2
// 369.686 us; speedup vs baseline: 1.4501x; 1.4501x over previous
//
#include <hip/hip_runtime.h>
#include <hip/hip_bf16.h>
#include <stdint.h>

typedef unsigned int u32;
typedef unsigned short u16;

#define F 128

typedef __attribute__((ext_vector_type(8))) short bf16x8;
typedef __attribute__((ext_vector_type(8))) u16 u16x8;
typedef __attribute__((ext_vector_type(4))) float f32x4;

__device__ __forceinline__ float bf2f(u16 v){
  union { u32 u; float f; } x; x.u = ((u32)v) << 16; return x.f;
}
__device__ __forceinline__ float bflo(u32 w){
  union { u32 u; float f; } x; x.u = w << 16; return x.f;       // 1 VALU
}
__device__ __forceinline__ float bfhi(u32 w){
  union { u32 u; float f; } x; x.u = w & 0xFFFF0000u; return x.f; // 1 VALU
}
__device__ __forceinline__ u16 f2bf(float f){
  union { float f; u32 u; } x; x.f = f;
  u32 u = x.u;
  return (u16)((u + 0x7fffu + ((u >> 16) & 1u)) >> 16);   // RNE
}

// ---- merged dtype / edge-layout detection -----------------------------------
// block 0: f32 words have uniform-random bits[14:7]; bf16 pair data of
// ~N(0,1)/glorot never has low-half "exponent" > 160  -> flags[1]
// block 1: int64 edge values < 50000 -> all odd 32b words are 0 -> flags[0]
__global__ void k_flags(const u32* __restrict__ xw, const u32* __restrict__ ei,
                        int* __restrict__ flags){
  if (blockIdx.x == 0){
    u32 hit = 0;
    for (int i = threadIdx.x; i < 2048; i += 256){
      u32 e = (xw[i] >> 7) & 0xFFu;
      if (e > 160u) hit = 1;
    }
    if (hit) atomicOr(&flags[1], 1);
  } else {
    u32 v = 0;
    for (int i = threadIdx.x; i < 4096; i += 256) v |= ei[2*i + 1];
    if (v) atomicOr(&flags[0], 1);
  }
}

// ---- bucketed CSR build (256-node buckets) ----------------------------------
__launch_bounds__(256)
__global__ void k_bhist(const u32* __restrict__ w, int E, const int* __restrict__ flagp,
                        int NB, int* __restrict__ bcnt){
  __shared__ int h[256];
  int st = (*flagp) ? 1 : 2;
  int t = threadIdx.x;
  h[t] = 0;
  __syncthreads();
  int base = blockIdx.x*4096;
  #pragma unroll 4
  for (int k = 0; k < 16; k++){
    int i = base + k*256 + t;
    if (i < E){
      int d = (int)w[(size_t)(E + i)*st];
      atomicAdd(&h[d >> 8], 1);
    }
  }
  __syncthreads();
  if (t < NB && h[t]) atomicAdd(&bcnt[t], h[t]);
}

__global__ void k_bscan(const int* __restrict__ bcnt, int NB, int E,
                        int* __restrict__ bbase, int* __restrict__ bump){
  __shared__ int s[256];
  int t = threadIdx.x;
  int v = (t < NB) ? bcnt[t] : 0;
  s[t] = v;
  __syncthreads();
  for (int off = 1; off < 256; off <<= 1){
    int x = (t >= off) ? s[t - off] : 0;
    __syncthreads();
    s[t] += x;
    __syncthreads();
  }
  bbase[t] = s[t] - v;            // exclusive; == E for t >= NB
  if (t == 255) bbase[256] = E;
  bump[t] = 0;
}

__launch_bounds__(256)
__global__ void k_msplit(const u32* __restrict__ w, int E, const int* __restrict__ flagp,
                         const int* __restrict__ bbase, int* __restrict__ bump,
                         u32* __restrict__ ebuf){
  __shared__ int h[256];
  __shared__ int cb[256];
  int st = (*flagp) ? 1 : 2;
  int t = threadIdx.x;
  h[t] = 0;
  __syncthreads();
  int base = blockIdx.x*4096;
  u32 ps[16]; int bk[16]; int rk[16];
  #pragma unroll 4
  for (int k = 0; k < 16; k++){
    int i = base + k*256 + t;
    if (i < E){
      u32 s = w[(size_t)i*st];
      u32 d = w[(size_t)(E + i)*st];
      bk[k] = (int)(d >> 8);
      ps[k] = (s & 0xFFFFu) | ((d & 0xFFu) << 16);
      rk[k] = atomicAdd(&h[bk[k]], 1);
    } else bk[k] = -1;
  }
  __syncthreads();
  cb[t] = h[t] ? (bbase[t] + atomicAdd(&bump[t], h[t])) : 0;
  __syncthreads();
  #pragma unroll 4
  for (int k = 0; k < 16; k++){
    if (bk[k] >= 0) ebuf[cb[bk[k]] + rk[k]] = ps[k];
  }
}

// per-bucket deg/rs/csr emit + dis = rsqrt(1+deg) folded in
__launch_bounds__(256)
__global__ void k_bemit(const u32* __restrict__ ebuf, const int* __restrict__ bbase,
                        int N, int* __restrict__ deg, int* __restrict__ rs,
                        u16* __restrict__ csr, float* __restrict__ dis){
  __shared__ int nd[256];
  __shared__ int nofs[256];
  __shared__ int s[256];
  int b = blockIdx.x;
  int t = threadIdx.x;
  int e0 = bbase[b], e1 = bbase[b + 1];
  nd[t] = 0;
  __syncthreads();
  for (int i = e0 + t; i < e1; i += 256) atomicAdd(&nd[ebuf[i] >> 16], 1);
  __syncthreads();
  int v = nd[t];
  s[t] = v;
  __syncthreads();
  for (int off = 1; off < 256; off <<= 1){
    int x = (t >= off) ? s[t - off] : 0;
    __syncthreads();
    s[t] += x;
    __syncthreads();
  }
  nofs[t] = s[t] - v;
  int node = b*256 + t;
  if (node < N){
    deg[node] = v;
    rs[node]  = e0 + nofs[t];
    dis[node] = rsqrtf(1.0f + (float)v);
  }
  nd[t] = 0;               // reuse as fill
  __syncthreads();
  for (int i = e0 + t; i < e1; i += 256){
    u32 p = ebuf[i];
    int d = (int)(p >> 16);
    int pos = e0 + nofs[d] + atomicAdd(&nd[d], 1);
    csr[pos] = (u16)(p & 0xFFFFu);
  }
}

// ---- merged small-tensor prep: bb[3][128], wf4[128], bb4[1] -----------------
__global__ void k_prep(const void* b1, const void* b2, const void* b3,
                       const void* W4, const void* b4, const int* __restrict__ isf32,
                       float* __restrict__ bb, float* __restrict__ wf4,
                       float* __restrict__ bb4){
  int t = threadIdx.x;
  int f32 = *isf32;
  if (t < 384){
    const void* s = (t < 128) ? b1 : ((t < 256) ? b2 : b3);
    int i = t & 127;
    bb[t] = f32 ? ((const float*)s)[i] : bf2f(((const u16*)s)[i]);
  } else if (t < 512){
    int i = t - 384;
    wf4[i] = f32 ? ((const float*)W4)[i] : bf2f(((const u16*)W4)[i]);
  } else if (t == 512){
    bb4[0] = f32 ? ((const float*)b4)[0] : bf2f(((const u16*)b4)[0]);
  }
}

// dual-dtype input -> bf16, row layout [N][128], 8 elems/thread
__global__ void k_cvt_b(const void* __restrict__ in, const int* __restrict__ isf32,
                        u16* __restrict__ out, int NF8){
  int i = blockIdx.x*256 + threadIdx.x;
  if (i >= NF8) return;
  u16x8 o;
  if (*isf32){
    const f32x4* p = (const f32x4*)in + i*2;
    f32x4 v0 = p[0], v1 = p[1];
    #pragma unroll
    for (int k = 0; k < 4; k++){ o[k] = f2bf(v0[k]); o[k+4] = f2bf(v1[k]); }
  } else {
    o = *((const u16x8*)in + i);
  }
  __builtin_nontemporal_store(o, (u16x8*)out + i);
}

// Swizzle W[128][128] x3 (dual dtype) into MFMA B-fragment order:
// WL[l][ct][kb][lane][j] = bf16(W[kb*32 + (lane>>4)*8 + j][ct*16 + (lane&15)])
__global__ void k_swz3(const void* W1, const void* W2, const void* W3,
                       const int* __restrict__ isf32, u16* __restrict__ WL){
  int l = blockIdx.x >> 6;
  const void* W = (l == 0) ? W1 : ((l == 1) ? W2 : W3);
  int idx = (blockIdx.x & 63)*256 + threadIdx.x;   // 0..16383
  int j    = idx & 7;
  int lane = (idx >> 3) & 63;
  int kb   = (idx >> 9) & 3;
  int ct   = idx >> 11;
  int m = lane & 15, q = lane >> 4;
  int k = kb*32 + q*8 + j;
  int c = ct*16 + m;
  float v = (*isf32) ? ((const float*)W)[k*F + c] : bf2f(((const u16*)W)[k*F + c]);
  WL[l*16384 + idx] = f2bf(v);
}

// G[r][c] = dis[r] * (X @ W)[r][c], MFMA 16x16x32 bf16. Block = 4 waves = 64 rows.
__launch_bounds__(256)
__global__ void k_mm(const u16* __restrict__ X, const u16* __restrict__ WL,
                     const float* __restrict__ dis, u16* __restrict__ G, int N){
  int w = threadIdx.x >> 6, lane = threadIdx.x & 63;
  int m = lane & 15, q = lane >> 4;
  int row0 = blockIdx.x*64 + w*16;
  int arow = row0 + m;
  bf16x8 a[4];
  if (arow < N){
    const u16* xp = X + (size_t)arow*F;
    #pragma unroll
    for (int kb = 0; kb < 4; kb++) a[kb] = *(const bf16x8*)(xp + kb*32 + q*8);
  } else {
    #pragma unroll
    for (int kb = 0; kb < 4; kb++) a[kb] = (bf16x8){0,0,0,0,0,0,0,0};
  }
  f32x4 acc[8];
  #pragma unroll
  for (int ct = 0; ct < 8; ct++) acc[ct] = (f32x4){0.f,0.f,0.f,0.f};
  #pragma unroll
  for (int ct = 0; ct < 8; ct++){
    #pragma unroll
    for (int kb = 0; kb < 4; kb++){
      bf16x8 b = *(const bf16x8*)(WL + ((size_t)((ct*4 + kb)*64 + lane))*8);
      acc[ct] = __builtin_amdgcn_mfma_f32_16x16x32_bf16(a[kb], b, acc[ct], 0, 0, 0);
    }
  }
  int rbase = row0 + q*4;
  #pragma unroll
  for (int r = 0; r < 4; r++){
    int row = rbase + r;
    if (row < N){
      float dv = dis[row];
      #pragma unroll
      for (int ct = 0; ct < 8; ct++)
        __builtin_nontemporal_store(f2bf(dv*acc[ct][r]),
                                    &G[(size_t)row*F + ct*16 + m]);
    }
  }
}

// wave-per-node row-gather aggregation, MLP-optimized:
// - neighbor ids pre-shifted to byte offsets once per 64-chunk
// - next chunk's index block prefetched before consuming current (no serial
//   csr->load chain between chunks)
// - 8 independent saddr-form loads in flight per group (progressive vmcnt)
__launch_bounds__(256)
__global__ void k_agg(const u16* __restrict__ G, const float* __restrict__ dis,
                      const int* __restrict__ rs, const int* __restrict__ deg,
                      const u16* __restrict__ csr, const float* __restrict__ bias,
                      u16* __restrict__ Xout, int N, int relu){
  int wid  = blockIdx.x*4 + (threadIdx.x >> 6);
  int lane = threadIdx.x & 63;
  if (wid >= N) return;
  int base = rs[wid], len = deg[wid];
  const char* Gb = (const char*)G;
  u32 fo = 4u*(u32)lane;                        // byte offset of my feature pair
  u32 sw = *(const u32*)(Gb + ((size_t)(u32)wid << 8) + fo);   // self row
  float a0 = bflo(sw), a1 = bfhi(sw);
  float pa[8], qa[8];
  #pragma unroll
  for (int k = 0; k < 8; k++){ pa[k] = 0.f; qa[k] = 0.f; }

  int mm = (len < 64) ? len : 64;
  u32 soff = 0;
  if (lane < mm) soff = ((u32)csr[base + lane]) << 8;
  int c0 = 0;
  while (c0 < len){
    int nxt = c0 + 64;
    u32 soff_n = 0;
    int nmm = len - nxt;
    if (nmm > 64) nmm = 64;
    if (nmm > 0 && lane < nmm) soff_n = ((u32)csr[base + nxt + lane]) << 8;
    int j = 0;
    for (; j + 8 <= mm; j += 8){
      u32 w[8];
      #pragma unroll
      for (int k = 0; k < 8; k++){
        u32 o = (u32)__builtin_amdgcn_readlane((int)soff, j + k);
        w[k] = *(const u32*)(Gb + o + fo);
      }
      #pragma unroll
      for (int k = 0; k < 8; k++){
        pa[k] += bflo(w[k]); qa[k] += bfhi(w[k]);
      }
    }
    for (; j < mm; j++){
      u32 o = (u32)__builtin_amdgcn_readlane((int)soff, j);
      u32 wv = *(const u32*)(Gb + o + fo);
      pa[0] += bflo(wv); qa[0] += bfhi(wv);
    }
    soff = soff_n; mm = nmm; c0 = nxt;
  }
  a0 += ((pa[0] + pa[1]) + (pa[2] + pa[3])) + ((pa[4] + pa[5]) + (pa[6] + pa[7]));
  a1 += ((qa[0] + qa[1]) + (qa[2] + qa[3])) + ((qa[4] + qa[5]) + (qa[6] + qa[7]));
  float dv = dis[wid];
  float o0 = fmaf(dv, a0, bias[2*lane]);
  float o1 = fmaf(dv, a1, bias[2*lane + 1]);
  if (relu){ o0 = fmaxf(o0, 0.f); o1 = fmaxf(o1, 0.f); }
  u32 pk = (u32)f2bf(o0) | ((u32)f2bf(o1) << 16);
  __builtin_nontemporal_store(pk, (u32*)(Xout + (size_t)wid*F + 2*lane));
}

// layer 4 matmul: G4[n] = dis[n] * dot(X[n,:], W4f[:,0]); one wave per node
__global__ void k_mm4(const u16* __restrict__ X, const float* __restrict__ W4f,
                      const float* __restrict__ dis, float* __restrict__ G4, int N){
  int gt   = blockIdx.x*blockDim.x + threadIdx.x;
  int wid  = gt >> 6;
  int lane = threadIdx.x & 63;
  if (wid >= N) return;
  u32 xw = *(const u32*)(X + (size_t)wid*F + 2*lane);
  float acc = bflo(xw)*W4f[2*lane] + bfhi(xw)*W4f[2*lane + 1];
  #pragma unroll
  for (int off = 32; off > 0; off >>= 1) acc += __shfl_down(acc, off, 64);
  if (lane == 0) G4[wid] = dis[wid]*acc;
}

__global__ void k_agg4(const float* __restrict__ G4, const float* __restrict__ dis,
                       const int* __restrict__ rs, const int* __restrict__ deg,
                       const u16* __restrict__ csr, const float* __restrict__ b4f,
                       const int* __restrict__ isf32, void* __restrict__ out, int N){
  int i = blockIdx.x*blockDim.x + threadIdx.x;
  if (i >= N) return;
  int base = rs[i], len = deg[i];
  float a0 = 0.f, a1 = 0.f, a2 = 0.f, a3 = 0.f;
  int j = 0;
  for (; j + 4 <= len; j += 4){
    int s0 = csr[base + j],     s1 = csr[base + j + 1];
    int s2 = csr[base + j + 2], s3 = csr[base + j + 3];
    a0 += G4[s0]; a1 += G4[s1]; a2 += G4[s2]; a3 += G4[s3];
  }
  for (; j < len; j++) a0 += G4[csr[base + j]];
  float r = dis[i]*(G4[i] + ((a0 + a1) + (a2 + a3))) + b4f[0];
  if (*isf32) ((float*)out)[i] = r;
  else        ((u16*)out)[i]   = f2bf(r);
}

extern "C" void kernel_launch(void* const* d_in, const int* in_sizes, int n_in,
                              void* d_out, int out_size, void* d_ws, size_t ws_size,
                              hipStream_t stream){
  const void* x0 = d_in[0];
  const u32*  ei = (const u32*)d_in[1];
  const void* Wp[4] = {d_in[2], d_in[4], d_in[6], d_in[8]};
  const void* bp[4] = {d_in[3], d_in[5], d_in[7], d_in[9]};
  int N = in_sizes[0] / F;       // 50000
  int E = in_sizes[1] / 2;       // 1,600,000
  int NB = (N + 255) >> 8;       // 196 buckets

  char* base = (char*)d_ws;
  size_t off = 0;
  auto alloc = [&](size_t bytes)->char*{
    char* p = base + off;
    off = (off + bytes + 255) & ~(size_t)255;
    return p;
  };
  int*   deg  = (int*)  alloc((size_t)N*4);
  float* dis  = (float*)alloc((size_t)N*4);
  int*   rs   = (int*)  alloc((size_t)N*4);
  float* g4   = (float*)alloc((size_t)N*4);
  int*   bcnt = (int*)  alloc(1024);
  int*   bbase= (int*)  alloc(1056);           // 257 ints
  int*   bump = (int*)  alloc(1024);
  int*   flags= (int*)  alloc(256);            // [0]=int32-edge flag, [1]=isf32
  u32*   ebuf = (u32*)  alloc((size_t)E*4);    // bucketed packed edges, 6.4 MB
  u16*   csr  = (u16*)  alloc((size_t)E*2);    // 3.2 MB
  u16*   WL   = (u16*)  alloc(3*16384*2);      // swizzled W1..W3, 96 KB
  float* wf4  = (float*)alloc(F*4);
  float* bb   = (float*)alloc(3*F*4);          // biases b1..b3
  float* bb4  = (float*)alloc(256);
  u16*   gbuf = (u16*)  alloc((size_t)N*F*2);  // 12.8 MB, row [N][128]
  u16*   xbuf = (u16*)  alloc((size_t)N*F*2);  // 12.8 MB, row [N][128]

  hipMemsetAsync(bcnt, 0, 1024, stream);
  hipMemsetAsync(flags, 0, 256, stream);

  int* eflag = flags + 0;
  int* isf32 = flags + 1;

  int nbt = (N + 255)/256;
  int etb = (E + 4095)/4096;

  k_flags <<<2, 256, 0, stream>>>((const u32*)x0, ei, flags);
  k_bhist <<<etb, 256, 0, stream>>>(ei, E, eflag, NB, bcnt);
  k_bscan <<<1, 256, 0, stream>>>(bcnt, NB, E, bbase, bump);
  k_msplit<<<etb, 256, 0, stream>>>(ei, E, eflag, bbase, bump, ebuf);
  k_bemit <<<NB, 256, 0, stream>>>(ebuf, bbase, N, deg, rs, csr, dis);
  k_prep  <<<1, 640, 0, stream>>>(bp[0], bp[1], bp[2], Wp[3], bp[3], isf32, bb, wf4, bb4);
  k_swz3  <<<192, 256, 0, stream>>>(Wp[0], Wp[1], Wp[2], isf32, WL);
  int NF8 = N*F/8;
  k_cvt_b <<<(NF8 + 255)/256, 256, 0, stream>>>(x0, isf32, xbuf, NF8);

  int mmb = (N + 63)/64;
  int agb = (N + 3)/4;

  for (int l = 0; l < 3; l++){
    k_mm <<<mmb, 256, 0, stream>>>(xbuf, WL + l*16384, dis, gbuf, N);
    k_agg<<<agb, 256, 0, stream>>>(gbuf, dis, rs, deg, csr, bb + l*F, xbuf, N, 1);
  }
  k_mm4 <<<((size_t)N*64 + 255)/256, 256, 0, stream>>>(xbuf, wf4, dis, g4, N);
  k_agg4<<<nbt, 256, 0, stream>>>(g4, dis, rs, deg, csr, bb4, isf32, (void*)d_out, N);
}